// Round 3
// baseline (358.382 us; speedup 1.0000x reference)
//
#include <hip/hip_runtime.h>
#include <math.h>

// ---------------- problem constants ----------------
#define GG   16      // stripes
#define KK   4       // latents per stripe
#define NN   64      // batch
#define CC   256     // channels
#define SHH  4       // stripe height
#define WW   44      // width
#define PP   176     // pixels per stripe
#define HWSZ 2816    // 64*44
#define CHW  720896  // CC*HWSZ
#define TOPKK 22     // int(176*0.125)

// ---------------- DPP wave64 ops (VALU pipe) ----------------
template<int CTRL, int RMASK>
__device__ __forceinline__ float dpp0(float v) {
    return __int_as_float(__builtin_amdgcn_update_dpp(
        0, __float_as_int(v), CTRL, RMASK, 0xF, true));
}
// wave_shr1 (0x138): D[i] = S[i-1], lane0 -> 0  (left neighbor)
__device__ __forceinline__ float nbrL(float v) { return dpp0<0x138, 0xF>(v); }
// wave_shl1 (0x130): D[i] = S[i+1], lane63 -> 0 (right neighbor)
__device__ __forceinline__ float nbrR(float v) { return dpp0<0x130, 0xF>(v); }

// sum of all 64 lanes; result valid on lane 63 only
__device__ __forceinline__ float wave_sum63(float v) {
    v += dpp0<0x111, 0xF>(v);
    v += dpp0<0x112, 0xF>(v);
    v += dpp0<0x114, 0xF>(v);
    v += dpp0<0x118, 0xF>(v);
    v += dpp0<0x142, 0xA>(v);   // bcast15 into rows 1,3
    v += dpp0<0x143, 0xC>(v);   // bcast31 into rows 2,3
    return v;
}
__device__ __forceinline__ float bcast63(float v) {
    return __int_as_float(__builtin_amdgcn_readlane(__float_as_int(v), 63));
}
__device__ __forceinline__ float wave_sum_all(float v) { return bcast63(wave_sum63(v)); }

// max over 64 lanes, broadcast; requires true max >= 0 (zero-fill safe)
__device__ __forceinline__ float wave_max_nn(float v) {
    v = fmaxf(v, dpp0<0x111, 0xF>(v));
    v = fmaxf(v, dpp0<0x112, 0xF>(v));
    v = fmaxf(v, dpp0<0x114, 0xF>(v));
    v = fmaxf(v, dpp0<0x118, 0xF>(v));
    v = fmaxf(v, dpp0<0x142, 0xA>(v));
    v = fmaxf(v, dpp0<0x143, 0xC>(v));
    return bcast63(v);
}

// ---------------- kernel 1: normalize latent basis ----------------
// lb: [G][K][C] -> lbn: [G][C][K] (float4 over k per (g,c))
__global__ __launch_bounds__(64) void norm_basis_kernel(
    const float* __restrict__ lb, float* __restrict__ lbn) {
    const int gk = blockIdx.x;
    const int lane = threadIdx.x;
    const float* row = lb + (size_t)gk * CC;
    float v0 = row[lane], v1 = row[lane + 64], v2 = row[lane + 128], v3 = row[lane + 192];
    float ss = v0 * v0 + v1 * v1 + v2 * v2 + v3 * v3;
    float tot = wave_sum_all(ss);
    float sc = 1.0f / fmaxf(sqrtf(tot), 1e-12f);
    const int g = gk >> 2, k = gk & 3;
    float* dst = lbn + (size_t)g * CC * 4 + k;
    dst[(size_t)lane * 4]         = v0 * sc;
    dst[(size_t)(lane + 64) * 4]  = v1 * sc;
    dst[(size_t)(lane + 128) * 4] = v2 * sc;
    dst[(size_t)(lane + 192) * 4] = v3 * sc;
}

// ---------------- fused main kernel ----------------
// grid (GG, NN), 512 threads = 8 waves. Wave w owns channels [w*32, w*32+32).
// Per channel: 4 stripe rows in registers, 3x3 pool via DPP neighbors
// (stripe-local zero pad => no cross-channel/cross-wave data needed).
__global__ __launch_bounds__(512, 8) void fused_kernel(
    const float* __restrict__ x, const float* __restrict__ lbn,
    float* __restrict__ pres_ws, float* __restrict__ tok_out,
    float4* __restrict__ outS, float4* __restrict__ outP) {
    const int g = blockIdx.x;
    const int n = blockIdx.y;
    const int tid = threadIdx.x;
    const int w = tid >> 6;
    const int lane = tid & 63;
    const bool al = lane < WW;

    // pd[w][p]: per-wave float4 d-partials; pd[0] becomes dsum after reduction;
    // pd[2] reused as sup4, pd[4] reused as pw4 (phase-1 data dead by then).
    __shared__ float4 pd[8][PP];     // 22528 B
    __shared__ float2 pnf[8][PP];    // 11264 B (nrm, fe partials; pnf[0] -> sums)
    __shared__ float redA[4], redB[4], zred[4][4];
    float4* sup4 = pd[2];
    float4* pw4  = pd[4];

    const float* xb = x + (size_t)n * CHW + g * PP;
    const float4* lbg = (const float4*)lbn + (g << 8);

    // ---- phase 1: per-wave pooled routing stats over 32 channels ----
    float4 dk[4];
    float nr[4] = {0, 0, 0, 0}, fe[4] = {0, 0, 0, 0};
    #pragma unroll
    for (int s = 0; s < 4; ++s) dk[s] = make_float4(0, 0, 0, 0);

    const int c0 = w * 32;
    float r0 = 0, r1 = 0, r2 = 0, r3 = 0;
    if (al) {
        const float* xc = xb + (size_t)c0 * HWSZ;
        r0 = xc[lane]; r1 = xc[lane + 44]; r2 = xc[lane + 88]; r3 = xc[lane + 132];
    }
    #pragma unroll 1
    for (int i = 0; i < 32; ++i) {
        float b0 = 0, b1 = 0, b2 = 0, b3 = 0;
        if (i < 31 && al) {
            const float* xn = xb + (size_t)(c0 + i + 1) * HWSZ;
            b0 = xn[lane]; b1 = xn[lane + 44]; b2 = xn[lane + 88]; b3 = xn[lane + 132];
        }
        float4 lb = lbg[c0 + i];   // wave-uniform -> scalar load
        fe[0] += r0 * r0; fe[1] += r1 * r1; fe[2] += r2 * r2; fe[3] += r3 * r3;
        float h0 = r0 + nbrL(r0) + nbrR(r0);
        float h1 = r1 + nbrL(r1) + nbrR(r1);
        float h2 = r2 + nbrL(r2) + nbrR(r2);
        float h3 = r3 + nbrL(r3) + nbrR(r3);
        const float k9 = 1.0f / 9.0f;
        float p0 = (h0 + h1) * k9;          // row -1 is zero pad
        float p1 = (h0 + h1 + h2) * k9;
        float p2 = (h1 + h2 + h3) * k9;
        float p3 = (h2 + h3) * k9;          // row 4 is zero pad
        nr[0] += p0 * p0; nr[1] += p1 * p1; nr[2] += p2 * p2; nr[3] += p3 * p3;
        dk[0].x += p0 * lb.x; dk[0].y += p0 * lb.y; dk[0].z += p0 * lb.z; dk[0].w += p0 * lb.w;
        dk[1].x += p1 * lb.x; dk[1].y += p1 * lb.y; dk[1].z += p1 * lb.z; dk[1].w += p1 * lb.w;
        dk[2].x += p2 * lb.x; dk[2].y += p2 * lb.y; dk[2].z += p2 * lb.z; dk[2].w += p2 * lb.w;
        dk[3].x += p3 * lb.x; dk[3].y += p3 * lb.y; dk[3].z += p3 * lb.z; dk[3].w += p3 * lb.w;
        r0 = b0; r1 = b1; r2 = b2; r3 = b3;
    }
    if (al) {
        #pragma unroll
        for (int s = 0; s < 4; ++s) {
            pd[w][s * 44 + lane]  = dk[s];
            pnf[w][s * 44 + lane] = make_float2(nr[s], fe[s]);
        }
    }
    __syncthreads();

    // ---- cross-wave reduction (in place into slot 0) ----
    if (tid < PP) {
        float4 a = pd[0][tid];
        #pragma unroll
        for (int ww = 1; ww < 8; ++ww) {
            float4 b = pd[ww][tid];
            a.x += b.x; a.y += b.y; a.z += b.z; a.w += b.w;
        }
        pd[0][tid] = a;
    } else if (tid >= 256 && tid < 256 + PP) {
        const int p = tid - 256;
        float2 a = pnf[0][p];
        #pragma unroll
        for (int ww = 1; ww < 8; ++ww) {
            float2 b = pnf[ww][p];
            a.x += b.x; a.y += b.y;
        }
        pnf[0][p] = a;
    }
    __syncthreads();

    // ---- finalize (all 8 waves compute redundantly; waves 0..3 write) ----
    const int s4 = w & 3;
    const int pix = s4 * 44 + (al ? lane : 0);
    float4 dv = pd[0][pix];
    float2 nf = pnf[0][pix];
    float nrm = nf.x;
    float fev = nf.y * (1.0f / 256.0f);

    float fmw = wave_max_nn(al ? fev : 0.0f);
    if (w < 4 && lane == 0) redA[s4] = fmw;
    __syncthreads();
    float femax = fmaxf(fmaxf(redA[0], redA[1]), fmaxf(redA[2], redA[3]));
    float den = fmaxf(femax, 1e-6f);
    bool pa = al && ((fev / den) > 0.05f);
    unsigned long long bl = __ballot((int)pa);
    if (w < 4 && lane == 0) redB[s4] = (float)__popcll(bl);
    __syncthreads();
    float cnt = redB[0] + redB[1] + redB[2] + redB[3];
    float actv = pa ? 1.0f : 0.0f;
    if (cnt <= 0.0f) actv = (al && (fev > 0.0f)) ? 1.0f : 0.0f;

    float inv = 8.0f / fmaxf(sqrtf(nrm), 1e-12f);   // 1/TEMP folded
    float L0 = dv.x * inv, L1 = dv.y * inv, L2 = dv.z * inv, L3 = dv.w * inv;
    float mx = fmaxf(fmaxf(L0, L1), fmaxf(L2, L3));
    float e0 = expf(L0 - mx), e1 = expf(L1 - mx), e2 = expf(L2 - mx), e3 = expf(L3 - mx);
    float esum = e0 + e1 + e2 + e3;
    float sc = actv / esum;
    float s0 = e0 * sc, s1 = e1 * sc, s2 = e2 * sc, s3 = e3 * sc;

    float z0 = wave_sum63(s0), z1 = wave_sum63(s1), z2 = wave_sum63(s2), z3 = wave_sum63(s3);
    if (w < 4 && lane == 63) { zred[s4][0] = z0; zred[s4][1] = z1; zred[s4][2] = z2; zred[s4][3] = z3; }
    __syncthreads();
    float Z0 = zred[0][0] + zred[1][0] + zred[2][0] + zred[3][0];
    float Z1 = zred[0][1] + zred[1][1] + zred[2][1] + zred[3][1];
    float Z2 = zred[0][2] + zred[1][2] + zred[2][2] + zred[3][2];
    float Z3 = zred[0][3] + zred[1][3] + zred[2][3] + zred[3][3];
    float q0 = s0 / fmaxf(Z0, 1e-6f);
    float q1 = s1 / fmaxf(Z1, 1e-6f);
    float q2 = s2 / fmaxf(Z2, 1e-6f);
    float q3 = s3 / fmaxf(Z3, 1e-6f);

    if (w < 4 && al) {
        sup4[pix] = make_float4(s0, s1, s2, s3);
        pw4[pix]  = make_float4(q0, q1, q2, q3);
    }
    __syncthreads();

    // ---- top-22 presence: wave k (0..3) ----
    if (w < 4) {
        const float* supf = (const float*)sup4;
        const int k = w;
        float v0 = supf[lane * 4 + k];
        float v1 = supf[(lane + 64) * 4 + k];
        float v2 = (lane < PP - 128) ? supf[(lane + 128) * 4 + k] : -1e30f;
        float tks = 0.0f;
        for (int it = 0; it < TOPKK; ++it) {
            float lm = fmaxf(v0, fmaxf(v1, v2));
            float M = wave_max_nn(lm);
            tks += M;
            unsigned long long mk = __ballot((int)(lm == M));
            int src = __ffsll(mk) - 1;
            if (lane == src) {
                if (v0 == M)      v0 = -1e30f;
                else if (v1 == M) v1 = -1e30f;
                else              v2 = -1e30f;
            }
        }
        if (lane == 0) pres_ws[(size_t)n * 64 + g * KK + k] = tks * (1.0f / (float)TOPKK);
    }

    // ---- direct scatter of support/pool_w into full-res outputs ----
    // block (n,g) owns output pixels g*PP .. g*PP+175; writes all 16 gk-quads.
    {
        const size_t obase = ((size_t)n * HWSZ + (size_t)g * PP) * 16;   // float4 units
        const float4 z = make_float4(0, 0, 0, 0);
        #pragma unroll 1
        for (int j = tid; j < PP * 16; j += 512) {
            const int px = j >> 4, q = j & 15;
            float4 vs = sup4[px];
            float4 vp = pw4[px];
            bool hit = (q == g);
            outS[obase + j] = hit ? vs : z;
            outP[obase + j] = hit ? vp : z;
        }
    }

    // ---- tokens: tok[c][k] = sum_p pw[p][k] * x[c][p]  (x slab re-read from L2/L3) ----
    {
        float4 pwa = pw4[lane];
        float4 pwb = pw4[lane + 64];
        float4 pwc = (lane < PP - 128) ? pw4[lane + 128] : make_float4(0, 0, 0, 0);
        float* tokg = tok_out + (size_t)n * CC * 64 + g * KK;
        const int cb = w * 32;
        const float* xc0 = xb + (size_t)cb * HWSZ;
        float a0 = xc0[lane];
        float a1 = xc0[lane + 64];
        float a2 = (lane < PP - 128) ? xc0[lane + 128] : 0.0f;
        #pragma unroll 1
        for (int i = 0; i < 32; ++i) {
            float b0 = 0, b1 = 0, b2 = 0;
            if (i < 31) {
                const float* xn = xb + (size_t)(cb + i + 1) * HWSZ;
                b0 = xn[lane]; b1 = xn[lane + 64];
                b2 = (lane < PP - 128) ? xn[lane + 128] : 0.0f;
            }
            float t0 = a0 * pwa.x + a1 * pwb.x + a2 * pwc.x;
            float t1 = a0 * pwa.y + a1 * pwb.y + a2 * pwc.y;
            float t2 = a0 * pwa.z + a1 * pwb.z + a2 * pwc.z;
            float t3 = a0 * pwa.w + a1 * pwb.w + a2 * pwc.w;
            t0 = wave_sum63(t0); t1 = wave_sum63(t1); t2 = wave_sum63(t2); t3 = wave_sum63(t3);
            if (lane == 63) {
                *(float4*)(tokg + (size_t)(cb + i) * 64) = make_float4(t0, t1, t2, t3);
            }
            a0 = b0; a1 = b1; a2 = b2;
        }
    }
}

// ---------------- presence normalization ----------------
__global__ __launch_bounds__(64) void presence_kernel(
    const float* __restrict__ pres_ws, float* __restrict__ outp) {
    const int n = blockIdx.x;
    const int lane = threadIdx.x;
    float v = pres_ws[(size_t)n * 64 + lane];
    float tot = wave_sum_all(v);
    outp[(size_t)n * 64 + lane] = v / fmaxf(tot, 1e-6f);
}

// ---------------- launch ----------------
extern "C" void kernel_launch(void* const* d_in, const int* in_sizes, int n_in,
                              void* d_out, int out_size, void* d_ws, size_t ws_size,
                              hipStream_t stream) {
    const float* x = (const float*)d_in[0];        // [64,256,64,44]
    const float* lb = (const float*)d_in[1];       // [16,4,256]
    float* ws = (float*)d_ws;
    float* lbn     = ws;               // 16384 floats
    float* pres_ws = lbn + 16384;      // 4096 floats

    float* out = (float*)d_out;
    float* tok  = out;                     // [64,256,64]
    float* pres = out + 1048576;           // [64,64]
    float* outS = out + 1052672;           // [64,2816,64]
    float* outP = outS + 11534336;         // [64,2816,64]

    norm_basis_kernel<<<GG * KK, 64, 0, stream>>>(lb, lbn);
    fused_kernel<<<dim3(GG, NN), 512, 0, stream>>>(
        x, lbn, pres_ws, tok, (float4*)outS, (float4*)outP);
    presence_kernel<<<NN, 64, 0, stream>>>(pres_ws, pres);
}

// Round 4
// 342.552 us; speedup vs baseline: 1.0462x; 1.0462x over previous
//
#include <hip/hip_runtime.h>
#include <math.h>

// ---------------- problem constants ----------------
#define GG   16      // stripes
#define KK   4       // latents per stripe
#define NN   64      // batch
#define CC   256     // channels
#define SHH  4       // stripe height
#define WW   44      // width
#define PP   176     // pixels per stripe
#define HWSZ 2816    // 64*44
#define CHW  720896  // CC*HWSZ
#define TOPKK 22     // int(176*0.125)

// ---------------- DPP wave64 ops (VALU pipe) ----------------
template<int CTRL, int RMASK>
__device__ __forceinline__ float dpp0(float v) {
    return __int_as_float(__builtin_amdgcn_update_dpp(
        0, __float_as_int(v), CTRL, RMASK, 0xF, true));
}
__device__ __forceinline__ float nbrL(float v) { return dpp0<0x138, 0xF>(v); } // wave_shr1
__device__ __forceinline__ float nbrR(float v) { return dpp0<0x130, 0xF>(v); } // wave_shl1

// sum of all 64 lanes; result valid on lane 63 only
__device__ __forceinline__ float wave_sum63(float v) {
    v += dpp0<0x111, 0xF>(v);
    v += dpp0<0x112, 0xF>(v);
    v += dpp0<0x114, 0xF>(v);
    v += dpp0<0x118, 0xF>(v);
    v += dpp0<0x142, 0xA>(v);   // bcast15 into rows 1,3
    v += dpp0<0x143, 0xC>(v);   // bcast31 into rows 2,3
    return v;
}
__device__ __forceinline__ float bcast63(float v) {
    return __int_as_float(__builtin_amdgcn_readlane(__float_as_int(v), 63));
}
__device__ __forceinline__ float wave_sum_all(float v) { return bcast63(wave_sum63(v)); }

// max over 64 lanes, broadcast; requires true max >= 0 (zero-fill safe)
__device__ __forceinline__ float wave_max_nn(float v) {
    v = fmaxf(v, dpp0<0x111, 0xF>(v));
    v = fmaxf(v, dpp0<0x112, 0xF>(v));
    v = fmaxf(v, dpp0<0x114, 0xF>(v));
    v = fmaxf(v, dpp0<0x118, 0xF>(v));
    v = fmaxf(v, dpp0<0x142, 0xA>(v));
    v = fmaxf(v, dpp0<0x143, 0xC>(v));
    return bcast63(v);
}

// ---------------- kernel 1: normalize latent basis (scaled by 1/9) -------------
// lb: [G][K][C] -> lbn: [G][C][K] (float4 over k). The 1/9 avg-pool factor is
// folded in here; routing uses raw 3x3 sums and inv = 72/sqrt(nrm_raw).
__global__ __launch_bounds__(64) void norm_basis_kernel(
    const float* __restrict__ lb, float* __restrict__ lbn) {
    const int gk = blockIdx.x;
    const int lane = threadIdx.x;
    const float* row = lb + (size_t)gk * CC;
    float v0 = row[lane], v1 = row[lane + 64], v2 = row[lane + 128], v3 = row[lane + 192];
    float ss = v0 * v0 + v1 * v1 + v2 * v2 + v3 * v3;
    float tot = wave_sum_all(ss);
    float sc = (1.0f / 9.0f) / fmaxf(sqrtf(tot), 1e-12f);
    const int g = gk >> 2, k = gk & 3;
    float* dst = lbn + (size_t)g * CC * 4 + k;
    dst[(size_t)lane * 4]         = v0 * sc;
    dst[(size_t)(lane + 64) * 4]  = v1 * sc;
    dst[(size_t)(lane + 128) * 4] = v2 * sc;
    dst[(size_t)(lane + 192) * 4] = v3 * sc;
}

// ---------------- routing kernel ----------------
// grid (GG, NN), 512 threads = 8 waves; wave w owns channels [w*32, w*32+32).
// Register 3x3 pooling via DPP; one LDS cross-wave reduction; finalize + topk;
// sup/pw written to small ws (5.8 MB) for token/scatter kernels.
__global__ __launch_bounds__(512, 8) void routing_kernel(
    const float* __restrict__ x, const float* __restrict__ lbn,
    float* __restrict__ sup_ws, float* __restrict__ pw_ws,
    float* __restrict__ pres_ws) {
    const int g = blockIdx.x;
    const int n = blockIdx.y;
    const int tid = threadIdx.x;
    const int w = __builtin_amdgcn_readfirstlane(tid >> 6);   // force SGPR
    const int lane = tid & 63;
    const bool al = lane < WW;

    __shared__ float4 pd[8][PP];     // per-wave d partials; pd[0] -> sum
    __shared__ float2 pnf[8][PP];    // (nrm, fe) partials; pnf[0] -> sum
    __shared__ float redA[4], redB[4], zred[4][4];
    float4* sup4 = pd[2];            // reused after reduction
    float4* pw4  = pd[4];

    const float* xb = x + (size_t)n * CHW + g * PP;
    const int c0 = w * 32;
    // uniform (SGPR) basis pointer -> s_load_dwordx4 in the loop
    const float4* lbq = (const float4*)lbn + (g << 8) + c0;

    float4 dk[4];
    float nr[4] = {0, 0, 0, 0}, fe[4] = {0, 0, 0, 0};
    #pragma unroll
    for (int s = 0; s < 4; ++s) dk[s] = make_float4(0, 0, 0, 0);

    // pointer-bump addressing: one base pointer, imm offsets 0/176/352/528 B
    const float* xp = xb + (size_t)c0 * HWSZ + lane;
    float r0 = 0, r1 = 0, r2 = 0, r3 = 0;
    if (al) { r0 = xp[0]; r1 = xp[44]; r2 = xp[88]; r3 = xp[132]; }
    xp += HWSZ;
    #pragma unroll 1
    for (int i = 0; i < 32; ++i) {
        float b0 = 0, b1 = 0, b2 = 0, b3 = 0;
        if (i < 31 && al) { b0 = xp[0]; b1 = xp[44]; b2 = xp[88]; b3 = xp[132]; }
        xp += HWSZ;
        float4 lbv = lbq[i];   // wave-uniform
        fe[0] += r0 * r0; fe[1] += r1 * r1; fe[2] += r2 * r2; fe[3] += r3 * r3;
        float h0 = r0 + nbrL(r0) + nbrR(r0);
        float h1 = r1 + nbrL(r1) + nbrR(r1);
        float h2 = r2 + nbrL(r2) + nbrR(r2);
        float h3 = r3 + nbrL(r3) + nbrR(r3);
        // raw 3x3 sums (1/9 folded into lbv; nrm fixed via inv=72/sqrt)
        float p0 = h0 + h1;          // row -1 zero pad
        float p1 = p0 + h2;
        float t23 = h2 + h3;
        float p2 = h1 + t23;
        float p3 = t23;              // row 4 zero pad
        nr[0] += p0 * p0; nr[1] += p1 * p1; nr[2] += p2 * p2; nr[3] += p3 * p3;
        dk[0].x += p0 * lbv.x; dk[0].y += p0 * lbv.y; dk[0].z += p0 * lbv.z; dk[0].w += p0 * lbv.w;
        dk[1].x += p1 * lbv.x; dk[1].y += p1 * lbv.y; dk[1].z += p1 * lbv.z; dk[1].w += p1 * lbv.w;
        dk[2].x += p2 * lbv.x; dk[2].y += p2 * lbv.y; dk[2].z += p2 * lbv.z; dk[2].w += p2 * lbv.w;
        dk[3].x += p3 * lbv.x; dk[3].y += p3 * lbv.y; dk[3].z += p3 * lbv.z; dk[3].w += p3 * lbv.w;
        r0 = b0; r1 = b1; r2 = b2; r3 = b3;
    }
    if (al) {
        #pragma unroll
        for (int s = 0; s < 4; ++s) {
            pd[w][s * 44 + lane]  = dk[s];
            pnf[w][s * 44 + lane] = make_float2(nr[s], fe[s]);
        }
    }
    __syncthreads();

    // ---- cross-wave reduction into slot 0 ----
    if (tid < PP) {
        float4 a = pd[0][tid];
        #pragma unroll
        for (int ww = 1; ww < 8; ++ww) {
            float4 b = pd[ww][tid];
            a.x += b.x; a.y += b.y; a.z += b.z; a.w += b.w;
        }
        pd[0][tid] = a;
    } else if (tid >= 256 && tid < 256 + PP) {
        const int p = tid - 256;
        float2 a = pnf[0][p];
        #pragma unroll
        for (int ww = 1; ww < 8; ++ww) {
            float2 b = pnf[ww][p];
            a.x += b.x; a.y += b.y;
        }
        pnf[0][p] = a;
    }
    __syncthreads();

    // ---- finalize (8 waves redundant; waves 0..3 write) ----
    const int s4 = w & 3;
    const int pix = s4 * 44 + (al ? lane : 0);
    float4 dv = pd[0][pix];
    float2 nf = pnf[0][pix];
    float nrm = nf.x;
    float fev = nf.y * (1.0f / 256.0f);

    float fmw = wave_max_nn(al ? fev : 0.0f);
    if (w < 4 && lane == 0) redA[s4] = fmw;
    __syncthreads();
    float femax = fmaxf(fmaxf(redA[0], redA[1]), fmaxf(redA[2], redA[3]));
    float den = fmaxf(femax, 1e-6f);
    bool pa = al && ((fev / den) > 0.05f);
    unsigned long long bl = __ballot((int)pa);
    if (w < 4 && lane == 0) redB[s4] = (float)__popcll(bl);
    __syncthreads();
    float cnt = redB[0] + redB[1] + redB[2] + redB[3];
    float actv = pa ? 1.0f : 0.0f;
    if (cnt <= 0.0f) actv = (al && (fev > 0.0f)) ? 1.0f : 0.0f;

    float inv = 72.0f / fmaxf(sqrtf(nrm), 9e-12f);   // 8/TEMP-norm on raw sums
    float L0 = dv.x * inv, L1 = dv.y * inv, L2 = dv.z * inv, L3 = dv.w * inv;
    float mx = fmaxf(fmaxf(L0, L1), fmaxf(L2, L3));
    float e0 = expf(L0 - mx), e1 = expf(L1 - mx), e2 = expf(L2 - mx), e3 = expf(L3 - mx);
    float esum = e0 + e1 + e2 + e3;
    float sc = actv / esum;
    float s0 = e0 * sc, s1 = e1 * sc, s2 = e2 * sc, s3 = e3 * sc;

    float z0 = wave_sum63(s0), z1 = wave_sum63(s1), z2 = wave_sum63(s2), z3 = wave_sum63(s3);
    if (w < 4 && lane == 63) { zred[s4][0] = z0; zred[s4][1] = z1; zred[s4][2] = z2; zred[s4][3] = z3; }
    __syncthreads();
    float Z0 = zred[0][0] + zred[1][0] + zred[2][0] + zred[3][0];
    float Z1 = zred[0][1] + zred[1][1] + zred[2][1] + zred[3][1];
    float Z2 = zred[0][2] + zred[1][2] + zred[2][2] + zred[3][2];
    float Z3 = zred[0][3] + zred[1][3] + zred[2][3] + zred[3][3];
    float q0 = s0 / fmaxf(Z0, 1e-6f);
    float q1 = s1 / fmaxf(Z1, 1e-6f);
    float q2 = s2 / fmaxf(Z2, 1e-6f);
    float q3 = s3 / fmaxf(Z3, 1e-6f);

    if (w < 4 && al) {
        float4 sv = make_float4(s0, s1, s2, s3);
        float4 qv = make_float4(q0, q1, q2, q3);
        sup4[pix] = sv;
        pw4[pix]  = qv;
        const size_t wsb = (size_t)(n * GG + g) * PP + pix;
        ((float4*)sup_ws)[wsb] = sv;
        ((float4*)pw_ws)[wsb]  = qv;
    }
    __syncthreads();

    // ---- top-22 presence: wave k (0..3) ----
    if (w < 4) {
        const float* supf = (const float*)sup4;
        const int k = w;
        float v0 = supf[lane * 4 + k];
        float v1 = supf[(lane + 64) * 4 + k];
        float v2 = (lane < PP - 128) ? supf[(lane + 128) * 4 + k] : -1e30f;
        float tks = 0.0f;
        for (int it = 0; it < TOPKK; ++it) {
            float lm = fmaxf(v0, fmaxf(v1, v2));
            float M = wave_max_nn(lm);
            tks += M;
            unsigned long long mk = __ballot((int)(lm == M));
            int src = __ffsll(mk) - 1;
            if (lane == src) {
                if (v0 == M)      v0 = -1e30f;
                else if (v1 == M) v1 = -1e30f;
                else              v2 = -1e30f;
            }
        }
        if (lane == 0) pres_ws[(size_t)n * 64 + g * KK + k] = tks * (1.0f / (float)TOPKK);
    }
}

// ---------------- token kernel ----------------
// grid (GG*4, NN), 256 threads = 4 waves; wave handles 16 channels.
// x slab re-read is L3-served (routing just streamed it).
__global__ __launch_bounds__(256, 8) void token_kernel(
    const float* __restrict__ x, const float* __restrict__ pw_ws,
    float* __restrict__ tok_out) {
    const int g = blockIdx.x & 15;
    const int chunk = blockIdx.x >> 4;
    const int n = blockIdx.y;
    const int w = __builtin_amdgcn_readfirstlane(threadIdx.x >> 6);
    const int lane = threadIdx.x & 63;

    const float4* pwq = (const float4*)pw_ws + (size_t)(n * GG + g) * PP;
    float4 pwa = pwq[lane];
    float4 pwb = pwq[lane + 64];
    float4 pwc = (lane < 48) ? pwq[lane + 128] : make_float4(0, 0, 0, 0);

    const int cb = chunk * 64 + w * 16;
    const float* xp = x + (size_t)n * CHW + g * PP + (size_t)cb * HWSZ + lane;
    float* tokg = tok_out + (size_t)n * CC * 64 + g * KK + (size_t)cb * 64;

    float a0 = xp[0];
    float a1 = xp[64];
    float a2 = (lane < 48) ? xp[128] : 0.0f;
    xp += HWSZ;
    #pragma unroll 1
    for (int i = 0; i < 16; ++i) {
        float b0 = 0, b1 = 0, b2 = 0;
        if (i < 15) {
            b0 = xp[0]; b1 = xp[64];
            if (lane < 48) b2 = xp[128];
        }
        xp += HWSZ;
        float t0 = a0 * pwa.x + a1 * pwb.x + a2 * pwc.x;
        float t1 = a0 * pwa.y + a1 * pwb.y + a2 * pwc.y;
        float t2 = a0 * pwa.z + a1 * pwb.z + a2 * pwc.z;
        float t3 = a0 * pwa.w + a1 * pwb.w + a2 * pwc.w;
        t0 = wave_sum63(t0); t1 = wave_sum63(t1); t2 = wave_sum63(t2); t3 = wave_sum63(t3);
        if (lane == 63) {
            *(float4*)(tokg + (size_t)i * 64) = make_float4(t0, t1, t2, t3);
        }
        a0 = b0; a1 = b1; a2 = b2;
    }
}

// ---------------- scatter kernel (pure streaming write) ----------------
// grid (GG, NN), 256 threads; block (n,g) owns output pixels [g*176, g*176+176).
__global__ __launch_bounds__(256, 8) void scatter_kernel(
    const float4* __restrict__ sup_ws4, const float4* __restrict__ pw_ws4,
    float4* __restrict__ outS, float4* __restrict__ outP) {
    const int g = blockIdx.x;
    const int n = blockIdx.y;
    const int t = threadIdx.x;
    __shared__ float4 ls[PP], lp[PP];
    const size_t wsb = (size_t)(n * GG + g) * PP;
    if (t < PP) { ls[t] = sup_ws4[wsb + t]; lp[t] = pw_ws4[wsb + t]; }
    __syncthreads();
    const size_t obase = ((size_t)n * HWSZ + (size_t)g * PP) * 16;
    const float4 z = make_float4(0, 0, 0, 0);
    #pragma unroll 1
    for (int j = t; j < PP * 16; j += 256) {
        const int px = j >> 4, q = j & 15;
        const bool hit = (q == g);
        outS[obase + j] = hit ? ls[px] : z;
        outP[obase + j] = hit ? lp[px] : z;
    }
}

// ---------------- presence normalization ----------------
__global__ __launch_bounds__(64) void presence_kernel(
    const float* __restrict__ pres_ws, float* __restrict__ outp) {
    const int n = blockIdx.x;
    const int lane = threadIdx.x;
    float v = pres_ws[(size_t)n * 64 + lane];
    float tot = wave_sum_all(v);
    outp[(size_t)n * 64 + lane] = v / fmaxf(tot, 1e-6f);
}

// ---------------- launch ----------------
extern "C" void kernel_launch(void* const* d_in, const int* in_sizes, int n_in,
                              void* d_out, int out_size, void* d_ws, size_t ws_size,
                              hipStream_t stream) {
    const float* x = (const float*)d_in[0];        // [64,256,64,44]
    const float* lb = (const float*)d_in[1];       // [16,4,256]
    float* ws = (float*)d_ws;
    // ws (floats): lbn 16384 | pres 4096 | sup 720896 | pw 720896  (~5.9 MB)
    float* lbn     = ws;
    float* pres_ws = lbn + 16384;
    float* sup_ws  = pres_ws + 4096;
    float* pw_ws   = sup_ws + 720896;

    float* out = (float*)d_out;
    float* tok  = out;                     // [64,256,64]
    float* pres = out + 1048576;           // [64,64]
    float* outS = out + 1052672;           // [64,2816,64]
    float* outP = outS + 11534336;         // [64,2816,64]

    norm_basis_kernel<<<GG * KK, 64, 0, stream>>>(lb, lbn);
    routing_kernel<<<dim3(GG, NN), 512, 0, stream>>>(x, lbn, sup_ws, pw_ws, pres_ws);
    token_kernel<<<dim3(GG * 4, NN), 256, 0, stream>>>(x, pw_ws, tok);   // x still L3-hot
    scatter_kernel<<<dim3(GG, NN), 256, 0, stream>>>(
        (const float4*)sup_ws, (const float4*)pw_ws, (float4*)outS, (float4*)outP);
    presence_kernel<<<NN, 64, 0, stream>>>(pres_ws, pres);
}